// Round 1
// baseline (139.223 us; speedup 1.0000x reference)
//
#include <hip/hip_runtime.h>

// Shapes: B=1, N=4096, C=256, H=8, d=32.
// ws layout (ushort elems):
//   Q[2][8][4096][32]          @ 0         (Q pre-scaled by d^-0.5*log2e)
//   K[2][8][4096][32]          @ KOFF
//   Vb[2][8][128][2][512]      @ VOFF      (V in PV B-frag LINEAR order:
//                                           per 32-key block kb, per 16-d tile,
//                                           elem (d_lo, slot) at
//                                           ((slot>>3)*16+d_lo)*8 + (slot&7))
//   WBF[24][8192]              @ WOFF      (W bf16, swizzled to B-frag order)

typedef __attribute__((ext_vector_type(8))) short short8;
typedef __attribute__((ext_vector_type(4))) float float4v;
typedef __attribute__((ext_vector_type(4))) unsigned int uint4v;

#define NTOK 4096
#define CDIM 256
#define HEADS 8
#define DHEAD 32

#define QOFF 0
#define KOFF (2*HEADS*NTOK*DHEAD)
#define VOFF (2*(2*HEADS*NTOK*DHEAD))
#define WOFF (3*(2*HEADS*NTOK*DHEAD))

__device__ inline unsigned short f2bf(float f) {
    union { float f; unsigned u; } v; v.f = f;
    unsigned r = v.u + 0x7FFFu + ((v.u >> 16) & 1u);   // RNE
    return (unsigned short)(r >> 16);
}

// exp2 + truncation-pack two S tiles (8 floats) into one PV A-fragment
__device__ inline short8 exp_pack(float4v S0, float4v S1) {
    union { float f; unsigned u; } u0,u1,u2,u3,u4,u5,u6,u7;
    u0.f = __builtin_amdgcn_exp2f(S0[0]);
    u1.f = __builtin_amdgcn_exp2f(S0[1]);
    u2.f = __builtin_amdgcn_exp2f(S0[2]);
    u3.f = __builtin_amdgcn_exp2f(S0[3]);
    u4.f = __builtin_amdgcn_exp2f(S1[0]);
    u5.f = __builtin_amdgcn_exp2f(S1[1]);
    u6.f = __builtin_amdgcn_exp2f(S1[2]);
    u7.f = __builtin_amdgcn_exp2f(S1[3]);
    union { short8 s8; uint4v u4v; } p;
    p.u4v[0] = __builtin_amdgcn_perm(u1.u, u0.u, 0x07060302u);
    p.u4v[1] = __builtin_amdgcn_perm(u3.u, u2.u, 0x07060302u);
    p.u4v[2] = __builtin_amdgcn_perm(u5.u, u4.u, 0x07060302u);
    p.u4v[3] = __builtin_amdgcn_perm(u7.u, u6.u, 0x07060302u);
    return p.s8;
}

// ---------------------------------------------------------------------------
// Kernel 0: W fp32 -> bf16, swizzled so a B-fragment is one contiguous 16B
// load: WBF[o32*8192 + (kk*2+nhalf)*512 + (quad*16+l16)*8 + j]
// ---------------------------------------------------------------------------
__global__ __launch_bounds__(256) void wconv_kernel(
    const float* __restrict__ W, unsigned short* __restrict__ ws)
{
    int idx = blockIdx.x*256 + threadIdx.x;    // [0, 24576): (row, col-octet)
    int R = idx >> 5, oct = idx & 31;
    int C = oct * 8;
    const float4* p = reinterpret_cast<const float4*>(W + R*CDIM + C);
    float4 a = p[0], b = p[1];
    short8 f;
    f[0]=(short)f2bf(a.x); f[1]=(short)f2bf(a.y); f[2]=(short)f2bf(a.z); f[3]=(short)f2bf(a.w);
    f[4]=(short)f2bf(b.x); f[5]=(short)f2bf(b.y); f[6]=(short)f2bf(b.z); f[7]=(short)f2bf(b.w);
    int o32 = R >> 5, r = R & 31;
    int kk = C >> 5, quad = (C >> 3) & 3;
    int dst = o32*8192 + (kk*2 + (r>>4))*512 + (quad*16 + (r&15))*8;
    *reinterpret_cast<short8*>(ws + WOFF + dst) = f;
}

// ---------------------------------------------------------------------------
// Kernel 1: t = x @ W^T (bf16 MFMA) + LayerNorm over d=32 groups.
// No LDS/barriers. grid = 1024: (row-tile 0..127) x (o-eighth 0..7, 3 o32s).
// ---------------------------------------------------------------------------
__global__ __launch_bounds__(256) void qkv_ln_kernel(
    const float* __restrict__ before, const float* __restrict__ after,
    const float* __restrict__ gamma, const float* __restrict__ beta,
    unsigned short* __restrict__ ws)
{
    const int tid  = threadIdx.x;
    const int lane = tid & 63;
    const int w    = tid >> 6;
    const int quad = lane >> 4;
    const int l16  = lane & 15;
    const int rt   = blockIdx.x >> 3;
    const int oq   = blockIdx.x & 7;

    const int mrow_frag = rt*64 + w*16 + l16;
    const int inp_f = mrow_frag >> 12;
    const int n_f   = mrow_frag & 4095;
    const float* x = inp_f ? after : before;

    short8 afrag[8];
#pragma unroll
    for (int kk = 0; kk < 8; kk++) {
        const float4* p = reinterpret_cast<const float4*>(x + n_f*CDIM + kk*32 + quad*8);
        float4 a = p[0], b = p[1];
        short8 f;
        f[0]=(short)f2bf(a.x); f[1]=(short)f2bf(a.y); f[2]=(short)f2bf(a.z); f[3]=(short)f2bf(a.w);
        f[4]=(short)f2bf(b.x); f[5]=(short)f2bf(b.y); f[6]=(short)f2bf(b.z); f[7]=(short)f2bf(b.w);
        afrag[kk] = f;
    }

    const float g0  = gamma[l16], g1  = gamma[16+l16];
    const float be0 = beta[l16],  be1 = beta[16+l16];
    const float cscale = 0.17677669529663687f * 1.4426950408889634f; // d^-0.5*log2e

    const int mrow_out  = rt*64 + w*16 + quad*4;
    const int inp_o     = mrow_out >> 12;
    const int n_o_base  = mrow_out & 4095;

    const unsigned short* wbf = ws + WOFF;

    for (int o32 = oq*3; o32 < oq*3 + 3; o32++) {
        const unsigned short* wb = wbf + o32*8192 + lane*8;
        float4v acc0 = {0.f,0.f,0.f,0.f}, acc1 = {0.f,0.f,0.f,0.f};
#pragma unroll
        for (int kk = 0; kk < 8; kk++) {
            short8 b0 = *reinterpret_cast<const short8*>(wb + (kk*2    )*512);
            short8 b1 = *reinterpret_cast<const short8*>(wb + (kk*2 + 1)*512);
            acc0 = __builtin_amdgcn_mfma_f32_16x16x32_bf16(afrag[kk], b0, acc0, 0,0,0);
            acc1 = __builtin_amdgcn_mfma_f32_16x16x32_bf16(afrag[kk], b1, acc1, 0,0,0);
        }

        const int which = o32 >> 3;     // 0=q 1=k 2=v
        const int h     = o32 & 7;
        unsigned short* qk = ws + (which == 0 ? QOFF : KOFF) + ((inp_o*HEADS + h)*NTOK)*DHEAD;
        unsigned short* vb = ws + VOFF + ((inp_o*HEADS + h)*128)*1024;
        const float qs = (which == 0) ? cscale : 1.0f;

#pragma unroll
        for (int i = 0; i < 4; i++) {
            float sum = acc0[i] + acc1[i];
            float sq  = acc0[i]*acc0[i] + acc1[i]*acc1[i];
#pragma unroll
            for (int m = 1; m < 16; m <<= 1) {
                sum += __shfl_xor(sum, m);
                sq  += __shfl_xor(sq,  m);
            }
            float mu   = sum * (1.0f/32.0f);
            float var  = sq * (1.0f/32.0f) - mu*mu;
            float rstd = rsqrtf(var + 1e-5f);
            float v0 = ((acc0[i]-mu)*rstd*g0 + be0) * qs;
            float v1 = ((acc1[i]-mu)*rstd*g1 + be1) * qs;
            int n = n_o_base + i;
            if (which < 2) {
                qk[n*DHEAD + l16]      = f2bf(v0);
                qk[n*DHEAD + 16 + l16] = f2bf(v1);
            } else {
                // B-frag linear layout: key n -> block kb, slot within block;
                // elem (d_lo, slot) at ((slot>>3)*16 + d_lo)*8 + (slot&7)
                int kb = n >> 5, ki = n & 31;
                int slot = ((ki & 15) >> 2)*8 + (ki & 3) + ((ki >> 4) << 2);
                int off  = ((slot >> 3)*16 + l16)*8 + (slot & 7);
                vb[kb*1024 + off]       = f2bf(v0);   // d = l16   (tile 0)
                vb[kb*1024 + 512 + off] = f2bf(v1);   // d = 16+l16 (tile 1)
            }
        }
    }
}

// ---------------------------------------------------------------------------
// Kernel 2: cross attention — barrier-free streaming, block = 4 waves = 4
// KEY-QUARTERS (1024 keys each), each wave computes ALL 64 q-rows.
// R16 change: register double-buffered K/V prefetch (distance 1 key-step,
// unroll-by-2 ping-pong so all load offsets are affine immediates). The 4
// L2 loads per step previously sat on the critical path of every step
// (S-MFMA waited vmcnt(0) right after issue); now loads for step t+1 are
// in flight while step t's MFMA+exp (~350 cyc) runs. Final prefetch (t=32)
// reads <=2KB past this head's K/V region — always inside ws, never used.
// grid 1024 flat, XCD-pinned (h,X).
// ---------------------------------------------------------------------------
__global__ __launch_bounds__(256, 4) void attn_kernel(
    const unsigned short* __restrict__ ws, float* __restrict__ out)
{
    __shared__ float comb[3][64][33];           // waves 1..3: [row][d0..31, l]

    // XCD-locality decode: xcd = b&7 -> combo = xcd*2 + (i>>6), qb = i&63
    const int b    = blockIdx.x;
    const int xcd  = b & 7;
    const int i_   = b >> 3;                    // 0..127
    const int combo = xcd*2 + (i_ >> 6);        // 0..15
    const int h  = combo & 7;
    const int X  = combo >> 3;
    const int qb = i_ & 63;                     // 64 q-rows per block

    const int qinp = 1 - X, kvinp = X;
    const int tid  = threadIdx.x;
    const int lane = tid & 63;
    const int w    = tid >> 6;                  // key-quarter 0..3
    const int quad = lane >> 4;
    const int l16  = lane & 15;

    const unsigned short* qbase = ws + QOFF + ((qinp*HEADS + h)*NTOK)*DHEAD;
    const unsigned short* kbase = ws + KOFF + ((kvinp*HEADS + h)*NTOK)*DHEAD;
    const unsigned short* vbase = ws + VOFF + ((kvinp*HEADS + h)*128)*1024;

    const int q0 = qb*64;
    // Q as B-operand: B[n=q=l16][k=d=quad*8+j] — 4 fragments cover 64 q
    short8 qf[4];
#pragma unroll
    for (int qi = 0; qi < 4; qi++)
        qf[qi] = *reinterpret_cast<const short8*>(qbase + (q0 + qi*16 + l16)*DHEAD + quad*8);

    // K as A-operand (coalesced 1KB); V as B-operand (B-frag-linear, 1KB/blk)
    const unsigned short* kp = kbase + (w*1024 + l16)*DHEAD + quad*8;
    const unsigned short* vp = vbase + (w*32)*1024 + lane*8;

    const short8 ones = {0x3F80,0x3F80,0x3F80,0x3F80,0x3F80,0x3F80,0x3F80,0x3F80};

    float4v O[4][2], L[4];
#pragma unroll
    for (int qi = 0; qi < 4; qi++) {
        O[qi][0] = (float4v){0,0,0,0};
        O[qi][1] = (float4v){0,0,0,0};
        L[qi]    = (float4v){0,0,0,0};
    }
    const float4v z = {0,0,0,0};

    // register double-buffer helpers (affine offsets; imm-foldable)
    #define LDK0(t) (*reinterpret_cast<const short8*>(kp + (t)*32*DHEAD))
    #define LDK1(t) (*reinterpret_cast<const short8*>(kp + ((t)*32 + 16)*DHEAD))
    #define LDV0(t) (*reinterpret_cast<const short8*>(vp + (t)*1024))
    #define LDV1(t) (*reinterpret_cast<const short8*>(vp + (t)*1024 + 512))

    #define STEP(kf0, kf1, v0, v1)                                                          \
        do {                                                                                \
            _Pragma("unroll")                                                               \
            for (int qi = 0; qi < 4; qi++) {                                                \
                float4v S0 = __builtin_amdgcn_mfma_f32_16x16x32_bf16(kf0, qf[qi], z, 0,0,0);\
                float4v S1 = __builtin_amdgcn_mfma_f32_16x16x32_bf16(kf1, qf[qi], z, 0,0,0);\
                short8 pf = exp_pack(S0, S1);                                               \
                O[qi][0] = __builtin_amdgcn_mfma_f32_16x16x32_bf16(pf, v0,   O[qi][0], 0,0,0);\
                O[qi][1] = __builtin_amdgcn_mfma_f32_16x16x32_bf16(pf, v1,   O[qi][1], 0,0,0);\
                L[qi]    = __builtin_amdgcn_mfma_f32_16x16x32_bf16(pf, ones, L[qi],    0,0,0);\
            }                                                                               \
        } while (0)

    // preload step 0 into buffer A
    short8 aK0 = LDK0(0), aK1 = LDK1(0), aV0 = LDV0(0), aV1 = LDV1(0);

    for (int t = 0; t < 32; t += 2) {           // 32-key steps over the quarter
        // prefetch t+1 into buffer B, then compute t from A
        short8 bK0 = LDK0(t+1), bK1 = LDK1(t+1), bV0 = LDV0(t+1), bV1 = LDV1(t+1);
        STEP(aK0, aK1, aV0, aV1);
        // prefetch t+2 into buffer A (t=30 -> t+2=32: past-end, in-ws, unused)
        aK0 = LDK0(t+2); aK1 = LDK1(t+2); aV0 = LDV0(t+2); aV1 = LDV1(t+2);
        STEP(bK0, bK1, bV0, bV1);
    }

    #undef LDK0
    #undef LDK1
    #undef LDV0
    #undef LDV1
    #undef STEP

    // merge the 4 key-quarters: waves 1..3 publish, wave 0 merges + writes.
    // L: row = q (quad*4+i within the qi tile), all cols equal.
    if (w > 0) {
#pragma unroll
        for (int qi = 0; qi < 4; qi++)
#pragma unroll
            for (int i = 0; i < 4; i++) {
                int row = qi*16 + quad*4 + i;
                comb[w-1][row][l16]      = O[qi][0][i];
                comb[w-1][row][16 + l16] = O[qi][1][i];
                if (l16 == 0) comb[w-1][row][32] = L[qi][i];
            }
    }
    __syncthreads();

    if (w == 0) {
        float* ob = out + (size_t)X*NTOK*CDIM + h*DHEAD;
#pragma unroll
        for (int qi = 0; qi < 4; qi++) {
#pragma unroll
            for (int i = 0; i < 4; i++) {
                int row = qi*16 + quad*4 + i;
                float l  = L[qi][i]    + comb[0][row][32]      + comb[1][row][32]      + comb[2][row][32];
                float a  = O[qi][0][i] + comb[0][row][l16]     + comb[1][row][l16]     + comb[2][row][l16];
                float bb = O[qi][1][i] + comb[0][row][16+l16]  + comb[1][row][16+l16]  + comb[2][row][16+l16];
                float inv = 1.0f / l;
                int orow = q0 + row;
                ob[orow*CDIM + l16]      = a  * inv;
                ob[orow*CDIM + 16 + l16] = bb * inv;
            }
        }
    }
}

extern "C" void kernel_launch(void* const* d_in, const int* in_sizes, int n_in,
                              void* d_out, int out_size, void* d_ws, size_t ws_size,
                              hipStream_t stream)
{
    const float* before = (const float*)d_in[0];
    const float* after  = (const float*)d_in[1];
    const float* W      = (const float*)d_in[2];
    const float* gamma  = (const float*)d_in[3];
    const float* beta   = (const float*)d_in[4];
    float* out          = (float*)d_out;
    unsigned short* ws  = (unsigned short*)d_ws;   // needs ~13.0 MB

    hipLaunchKernelGGL(wconv_kernel, dim3(96), dim3(256), 0, stream, W, ws);
    hipLaunchKernelGGL(qkv_ln_kernel, dim3(1024), dim3(256), 0, stream,
                       before, after, gamma, beta, ws);
    hipLaunchKernelGGL(attn_kernel, dim3(1024), dim3(256), 0, stream, ws, out);
}

// Round 2
// 135.405 us; speedup vs baseline: 1.0282x; 1.0282x over previous
//
#include <hip/hip_runtime.h>

// Shapes: B=1, N=4096, C=256, H=8, d=32.
// ws layout (ushort elems):
//   Q[2][8][4096][32]          @ 0         (Q pre-scaled by d^-0.5*log2e)
//   K[2][8][4096][32]          @ KOFF
//   Vb[2][8][128][2][512]      @ VOFF      (V in PV B-frag LINEAR order:
//                                           per 32-key block kb, per 16-d tile,
//                                           elem (d_lo, slot) at
//                                           ((slot>>3)*16+d_lo)*8 + (slot&7))
//   WBF[24][8192]              @ WOFF      (W bf16, swizzled to B-frag order)

typedef __attribute__((ext_vector_type(8))) short short8;
typedef __attribute__((ext_vector_type(4))) float float4v;
typedef __attribute__((ext_vector_type(4))) unsigned int uint4v;

#define NTOK 4096
#define CDIM 256
#define HEADS 8
#define DHEAD 32

#define QOFF 0
#define KOFF (2*HEADS*NTOK*DHEAD)
#define VOFF (2*(2*HEADS*NTOK*DHEAD))
#define WOFF (3*(2*HEADS*NTOK*DHEAD))

__device__ inline unsigned short f2bf(float f) {
    union { float f; unsigned u; } v; v.f = f;
    unsigned r = v.u + 0x7FFFu + ((v.u >> 16) & 1u);   // RNE
    return (unsigned short)(r >> 16);
}

// exp2 + truncation-pack two S tiles (8 floats) into one PV A-fragment
__device__ inline short8 exp_pack(float4v S0, float4v S1) {
    union { float f; unsigned u; } u0,u1,u2,u3,u4,u5,u6,u7;
    u0.f = __builtin_amdgcn_exp2f(S0[0]);
    u1.f = __builtin_amdgcn_exp2f(S0[1]);
    u2.f = __builtin_amdgcn_exp2f(S0[2]);
    u3.f = __builtin_amdgcn_exp2f(S0[3]);
    u4.f = __builtin_amdgcn_exp2f(S1[0]);
    u5.f = __builtin_amdgcn_exp2f(S1[1]);
    u6.f = __builtin_amdgcn_exp2f(S1[2]);
    u7.f = __builtin_amdgcn_exp2f(S1[3]);
    union { short8 s8; uint4v u4v; } p;
    p.u4v[0] = __builtin_amdgcn_perm(u1.u, u0.u, 0x07060302u);
    p.u4v[1] = __builtin_amdgcn_perm(u3.u, u2.u, 0x07060302u);
    p.u4v[2] = __builtin_amdgcn_perm(u5.u, u4.u, 0x07060302u);
    p.u4v[3] = __builtin_amdgcn_perm(u7.u, u6.u, 0x07060302u);
    return p.s8;
}

// ---------------------------------------------------------------------------
// Kernel 0: W fp32 -> bf16, swizzled so a B-fragment is one contiguous 16B
// load: WBF[o32*8192 + (kk*2+nhalf)*512 + (quad*16+l16)*8 + j]
// ---------------------------------------------------------------------------
__global__ __launch_bounds__(256) void wconv_kernel(
    const float* __restrict__ W, unsigned short* __restrict__ ws)
{
    int idx = blockIdx.x*256 + threadIdx.x;    // [0, 24576): (row, col-octet)
    int R = idx >> 5, oct = idx & 31;
    int C = oct * 8;
    const float4* p = reinterpret_cast<const float4*>(W + R*CDIM + C);
    float4 a = p[0], b = p[1];
    short8 f;
    f[0]=(short)f2bf(a.x); f[1]=(short)f2bf(a.y); f[2]=(short)f2bf(a.z); f[3]=(short)f2bf(a.w);
    f[4]=(short)f2bf(b.x); f[5]=(short)f2bf(b.y); f[6]=(short)f2bf(b.z); f[7]=(short)f2bf(b.w);
    int o32 = R >> 5, r = R & 31;
    int kk = C >> 5, quad = (C >> 3) & 3;
    int dst = o32*8192 + (kk*2 + (r>>4))*512 + (quad*16 + (r&15))*8;
    *reinterpret_cast<short8*>(ws + WOFF + dst) = f;
}

// ---------------------------------------------------------------------------
// Kernel 1: t = x @ W^T (bf16 MFMA) + LayerNorm over d=32 groups.
// No LDS/barriers. grid = 1024: (row-tile 0..127) x (o-eighth 0..7, 3 o32s).
// ---------------------------------------------------------------------------
__global__ __launch_bounds__(256) void qkv_ln_kernel(
    const float* __restrict__ before, const float* __restrict__ after,
    const float* __restrict__ gamma, const float* __restrict__ beta,
    unsigned short* __restrict__ ws)
{
    const int tid  = threadIdx.x;
    const int lane = tid & 63;
    const int w    = tid >> 6;
    const int quad = lane >> 4;
    const int l16  = lane & 15;
    const int rt   = blockIdx.x >> 3;
    const int oq   = blockIdx.x & 7;

    const int mrow_frag = rt*64 + w*16 + l16;
    const int inp_f = mrow_frag >> 12;
    const int n_f   = mrow_frag & 4095;
    const float* x = inp_f ? after : before;

    short8 afrag[8];
#pragma unroll
    for (int kk = 0; kk < 8; kk++) {
        const float4* p = reinterpret_cast<const float4*>(x + n_f*CDIM + kk*32 + quad*8);
        float4 a = p[0], b = p[1];
        short8 f;
        f[0]=(short)f2bf(a.x); f[1]=(short)f2bf(a.y); f[2]=(short)f2bf(a.z); f[3]=(short)f2bf(a.w);
        f[4]=(short)f2bf(b.x); f[5]=(short)f2bf(b.y); f[6]=(short)f2bf(b.z); f[7]=(short)f2bf(b.w);
        afrag[kk] = f;
    }

    const float g0  = gamma[l16], g1  = gamma[16+l16];
    const float be0 = beta[l16],  be1 = beta[16+l16];
    const float cscale = 0.17677669529663687f * 1.4426950408889634f; // d^-0.5*log2e

    const int mrow_out  = rt*64 + w*16 + quad*4;
    const int inp_o     = mrow_out >> 12;
    const int n_o_base  = mrow_out & 4095;

    const unsigned short* wbf = ws + WOFF;

    for (int o32 = oq*3; o32 < oq*3 + 3; o32++) {
        const unsigned short* wb = wbf + o32*8192 + lane*8;
        float4v acc0 = {0.f,0.f,0.f,0.f}, acc1 = {0.f,0.f,0.f,0.f};
#pragma unroll
        for (int kk = 0; kk < 8; kk++) {
            short8 b0 = *reinterpret_cast<const short8*>(wb + (kk*2    )*512);
            short8 b1 = *reinterpret_cast<const short8*>(wb + (kk*2 + 1)*512);
            acc0 = __builtin_amdgcn_mfma_f32_16x16x32_bf16(afrag[kk], b0, acc0, 0,0,0);
            acc1 = __builtin_amdgcn_mfma_f32_16x16x32_bf16(afrag[kk], b1, acc1, 0,0,0);
        }

        const int which = o32 >> 3;     // 0=q 1=k 2=v
        const int h     = o32 & 7;
        unsigned short* qk = ws + (which == 0 ? QOFF : KOFF) + ((inp_o*HEADS + h)*NTOK)*DHEAD;
        unsigned short* vb = ws + VOFF + ((inp_o*HEADS + h)*128)*1024;
        const float qs = (which == 0) ? cscale : 1.0f;

#pragma unroll
        for (int i = 0; i < 4; i++) {
            float sum = acc0[i] + acc1[i];
            float sq  = acc0[i]*acc0[i] + acc1[i]*acc1[i];
#pragma unroll
            for (int m = 1; m < 16; m <<= 1) {
                sum += __shfl_xor(sum, m);
                sq  += __shfl_xor(sq,  m);
            }
            float mu   = sum * (1.0f/32.0f);
            float var  = sq * (1.0f/32.0f) - mu*mu;
            float rstd = rsqrtf(var + 1e-5f);
            float v0 = ((acc0[i]-mu)*rstd*g0 + be0) * qs;
            float v1 = ((acc1[i]-mu)*rstd*g1 + be1) * qs;
            int n = n_o_base + i;
            if (which < 2) {
                qk[n*DHEAD + l16]      = f2bf(v0);
                qk[n*DHEAD + 16 + l16] = f2bf(v1);
            } else {
                // B-frag linear layout: key n -> block kb, slot within block;
                // elem (d_lo, slot) at ((slot>>3)*16 + d_lo)*8 + (slot&7)
                int kb = n >> 5, ki = n & 31;
                int slot = ((ki & 15) >> 2)*8 + (ki & 3) + ((ki >> 4) << 2);
                int off  = ((slot >> 3)*16 + l16)*8 + (slot & 7);
                vb[kb*1024 + off]       = f2bf(v0);   // d = l16   (tile 0)
                vb[kb*1024 + 512 + off] = f2bf(v1);   // d = 16+l16 (tile 1)
            }
        }
    }
}

// ---------------------------------------------------------------------------
// Kernel 2: cross attention — barrier-free streaming, block = 4 waves = 4
// KEY-QUARTERS (1024 keys each), each wave computes ALL 64 q-rows.
// R17 change (T15 double-pipeline, minimal-register form): the post-exp P
// fragments pf[4] (16 VGPR) are carried ONE KEY-STEP forward. Iteration t
// issues S-MFMAs for step t, PV-MFMAs consuming pf from step t-1 (matrix
// work fully independent of this step's exp), and exp_pack(S(t)) whose
// result isn't needed until t+1 — exp latency leaves the critical path and
// every wave always has independent MFMA work while its exps run.
// (R16's load ping-pong is reverted: compiler re-sank the loads and it
// regressed 48->54 µs. Loads stay at use sites; compiler schedules them.)
// grid 1024 flat, XCD-pinned (h,X).
// ---------------------------------------------------------------------------
__global__ __launch_bounds__(256, 4) void attn_kernel(
    const unsigned short* __restrict__ ws, float* __restrict__ out)
{
    __shared__ float comb[3][64][33];           // waves 1..3: [row][d0..31, l]

    // XCD-locality decode: xcd = b&7 -> combo = xcd*2 + (i>>6), qb = i&63
    const int b    = blockIdx.x;
    const int xcd  = b & 7;
    const int i_   = b >> 3;                    // 0..127
    const int combo = xcd*2 + (i_ >> 6);        // 0..15
    const int h  = combo & 7;
    const int X  = combo >> 3;
    const int qb = i_ & 63;                     // 64 q-rows per block

    const int qinp = 1 - X, kvinp = X;
    const int tid  = threadIdx.x;
    const int lane = tid & 63;
    const int w    = tid >> 6;                  // key-quarter 0..3
    const int quad = lane >> 4;
    const int l16  = lane & 15;

    const unsigned short* qbase = ws + QOFF + ((qinp*HEADS + h)*NTOK)*DHEAD;
    const unsigned short* kbase = ws + KOFF + ((kvinp*HEADS + h)*NTOK)*DHEAD;
    const unsigned short* vbase = ws + VOFF + ((kvinp*HEADS + h)*128)*1024;

    const int q0 = qb*64;
    // Q as B-operand: B[n=q=l16][k=d=quad*8+j] — 4 fragments cover 64 q
    short8 qf[4];
#pragma unroll
    for (int qi = 0; qi < 4; qi++)
        qf[qi] = *reinterpret_cast<const short8*>(qbase + (q0 + qi*16 + l16)*DHEAD + quad*8);

    // K as A-operand (coalesced 1KB); V as B-operand (B-frag-linear, 1KB/blk)
    const unsigned short* kp = kbase + (w*1024 + l16)*DHEAD + quad*8;
    const unsigned short* vp = vbase + (w*32)*1024 + lane*8;

    const short8 ones = {0x3F80,0x3F80,0x3F80,0x3F80,0x3F80,0x3F80,0x3F80,0x3F80};

    float4v O[4][2], L[4];
#pragma unroll
    for (int qi = 0; qi < 4; qi++) {
        O[qi][0] = (float4v){0,0,0,0};
        O[qi][1] = (float4v){0,0,0,0};
        L[qi]    = (float4v){0,0,0,0};
    }
    const float4v z = {0,0,0,0};

    // --- software-pipelined softmax: pf carries exp(S(t-1)) ---
    short8 pf[4];

    {   // prologue: S(0) -> pf
        short8 kf0 = *reinterpret_cast<const short8*>(kp);
        short8 kf1 = *reinterpret_cast<const short8*>(kp + 16*DHEAD);
#pragma unroll
        for (int qi = 0; qi < 4; qi++) {
            float4v S0 = __builtin_amdgcn_mfma_f32_16x16x32_bf16(kf0, qf[qi], z, 0,0,0);
            float4v S1 = __builtin_amdgcn_mfma_f32_16x16x32_bf16(kf1, qf[qi], z, 0,0,0);
            pf[qi] = exp_pack(S0, S1);
        }
    }

    for (int t = 1; t < 32; t++) {
        short8 kf0 = *reinterpret_cast<const short8*>(kp + (t*32     )*DHEAD);
        short8 kf1 = *reinterpret_cast<const short8*>(kp + (t*32 + 16)*DHEAD);
        short8 v0  = *reinterpret_cast<const short8*>(vp + (t-1)*1024);
        short8 v1  = *reinterpret_cast<const short8*>(vp + (t-1)*1024 + 512);
#pragma unroll
        for (int qi = 0; qi < 4; qi++) {
            // S for step t (matrix pipe; independent of pf)
            float4v S0 = __builtin_amdgcn_mfma_f32_16x16x32_bf16(kf0, qf[qi], z, 0,0,0);
            float4v S1 = __builtin_amdgcn_mfma_f32_16x16x32_bf16(kf1, qf[qi], z, 0,0,0);
            // PV for step t-1 (matrix pipe; consumes OLD pf — no exp wait)
            O[qi][0] = __builtin_amdgcn_mfma_f32_16x16x32_bf16(pf[qi], v0,   O[qi][0], 0,0,0);
            O[qi][1] = __builtin_amdgcn_mfma_f32_16x16x32_bf16(pf[qi], v1,   O[qi][1], 0,0,0);
            L[qi]    = __builtin_amdgcn_mfma_f32_16x16x32_bf16(pf[qi], ones, L[qi],    0,0,0);
            // exp for step t (VALU/trans; result not needed until t+1)
            pf[qi] = exp_pack(S0, S1);
        }
    }

    {   // epilogue: PV for step 31
        short8 v0 = *reinterpret_cast<const short8*>(vp + 31*1024);
        short8 v1 = *reinterpret_cast<const short8*>(vp + 31*1024 + 512);
#pragma unroll
        for (int qi = 0; qi < 4; qi++) {
            O[qi][0] = __builtin_amdgcn_mfma_f32_16x16x32_bf16(pf[qi], v0,   O[qi][0], 0,0,0);
            O[qi][1] = __builtin_amdgcn_mfma_f32_16x16x32_bf16(pf[qi], v1,   O[qi][1], 0,0,0);
            L[qi]    = __builtin_amdgcn_mfma_f32_16x16x32_bf16(pf[qi], ones, L[qi],    0,0,0);
        }
    }

    // merge the 4 key-quarters: waves 1..3 publish, wave 0 merges + writes.
    // L: row = q (quad*4+i within the qi tile), all cols equal.
    if (w > 0) {
#pragma unroll
        for (int qi = 0; qi < 4; qi++)
#pragma unroll
            for (int i = 0; i < 4; i++) {
                int row = qi*16 + quad*4 + i;
                comb[w-1][row][l16]      = O[qi][0][i];
                comb[w-1][row][16 + l16] = O[qi][1][i];
                if (l16 == 0) comb[w-1][row][32] = L[qi][i];
            }
    }
    __syncthreads();

    if (w == 0) {
        float* ob = out + (size_t)X*NTOK*CDIM + h*DHEAD;
#pragma unroll
        for (int qi = 0; qi < 4; qi++) {
#pragma unroll
            for (int i = 0; i < 4; i++) {
                int row = qi*16 + quad*4 + i;
                float l  = L[qi][i]    + comb[0][row][32]      + comb[1][row][32]      + comb[2][row][32];
                float a  = O[qi][0][i] + comb[0][row][l16]     + comb[1][row][l16]     + comb[2][row][l16];
                float bb = O[qi][1][i] + comb[0][row][16+l16]  + comb[1][row][16+l16]  + comb[2][row][16+l16];
                float inv = 1.0f / l;
                int orow = q0 + row;
                ob[orow*CDIM + l16]      = a  * inv;
                ob[orow*CDIM + 16 + l16] = bb * inv;
            }
        }
    }
}

extern "C" void kernel_launch(void* const* d_in, const int* in_sizes, int n_in,
                              void* d_out, int out_size, void* d_ws, size_t ws_size,
                              hipStream_t stream)
{
    const float* before = (const float*)d_in[0];
    const float* after  = (const float*)d_in[1];
    const float* W      = (const float*)d_in[2];
    const float* gamma  = (const float*)d_in[3];
    const float* beta   = (const float*)d_in[4];
    float* out          = (float*)d_out;
    unsigned short* ws  = (unsigned short*)d_ws;   // needs ~13.0 MB

    hipLaunchKernelGGL(wconv_kernel, dim3(96), dim3(256), 0, stream, W, ws);
    hipLaunchKernelGGL(qkv_ln_kernel, dim3(1024), dim3(256), 0, stream,
                       before, after, gamma, beta, ws);
    hipLaunchKernelGGL(attn_kernel, dim3(1024), dim3(256), 0, stream, ws, out);
}